// Round 1
// baseline (745.884 us; speedup 1.0000x reference)
//
#include <hip/hip_runtime.h>
#include <math.h>

#define N_NODES 512
#define QLEN    1024
#define DIM     256
#define TJ      16            // context rows per tile
#define LROW    264           // padded LDS row stride (floats): 264%32==8 -> 2-way (free)
#define NT      (QLEN / TJ)   // 64 tiles

#define AS1 __attribute__((address_space(1)))
#define AS3 __attribute__((address_space(3)))
#define GLD16(gsrc, ldst) \
  __builtin_amdgcn_global_load_lds((AS1 const void*)(gsrc), (AS3 void*)(ldst), 16, 0, 0)

// ---------------------------------------------------------------------------
// K1: fused  q = query@W_in^T ; scores = q.ctx ; online softmax ; A,B sums
// one block per node, 256 threads (4 waves). Single pass over context.
// ---------------------------------------------------------------------------
__global__ __launch_bounds__(256, 2) void attn_main_kernel(
    const float* __restrict__ query,    // [N,1,D]
    const float* __restrict__ context,  // [N,Q,D]
    const float* __restrict__ W_in,     // [D,D]
    const float* __restrict__ ae,
    const float* __restrict__ ad,
    const float* __restrict__ ab,
    float* __restrict__ scores_out,     // d_out + N*D : raw scores [N,Q]
    float* __restrict__ q_ws,           // [N,D]
    float* __restrict__ mix2_ws,        // [N,D]
    float* __restrict__ ml_ws)          // [N,2] (m, l)
{
  __shared__ float qs[DIM];
  __shared__ float qv[DIM];
  __shared__ float sc_all[QLEN];            // raw scores for this node
  __shared__ float tile[2][TJ * LROW];      // double-buffered context tile

  const int b    = blockIdx.x;
  const int tid  = threadIdx.x;
  const int wave = tid >> 6;
  const int lane = tid & 63;
  const int grp  = tid >> 4;   // 0..15 : which tile row this thread's dot works on
  const int gl   = tid & 15;   // lane within 16-lane dot group

  const float* ctx = context + (size_t)b * QLEN * DIM;

  qs[tid] = query[b * DIM + tid];
  __syncthreads();

  // issue async prefetch of tile 0 into buffer 0 (overlaps q projection)
  #pragma unroll
  for (int i = 0; i < 4; ++i) {
    const int r = wave + i * 4;                       // wave stages rows w, w+4, w+8, w+12
    GLD16(ctx + (size_t)r * DIM + lane * 4, &tile[0][r * LROW]);
  }

  // q projection: qv[tid] = sum_k W_in[tid,k] * qs[k]   (W_in is L2/L3-resident)
  float acc = 0.f;
  {
    const float4* w4 = (const float4*)(W_in + (size_t)tid * DIM);
    #pragma unroll 8
    for (int k = 0; k < DIM / 4; ++k) {
      const float4 wv = w4[k];
      acc += wv.x * qs[4 * k] + wv.y * qs[4 * k + 1] +
             wv.z * qs[4 * k + 2] + wv.w * qs[4 * k + 3];
    }
  }
  qv[tid] = acc;
  q_ws[b * DIM + tid] = acc;

  const float ab_v = ab[b];

  float m = -INFINITY;
  float l = 0.f;
  float accA = 0.f;   // thread owns dim d = tid :  sum_j w_j * ctx[j,d]
  float accB = 0.f;   //                            sum_j w_j * bt_j * |ctx[j,d]|

  for (int t = 0; t < NT; ++t) {
    const int cur = t & 1;

    // full barrier: compiler drains vmcnt(0) -> tile t resident; qv visible (t==0);
    // all waves done reading buffer (cur^1) from iteration t-1 -> safe to overwrite.
    __syncthreads();

    // issue async prefetch of tile t+1 into the other buffer (stays in flight
    // across the lgkm-only mid barrier below).
    if (t + 1 < NT) {
      const float* src = ctx + (size_t)(t + 1) * TJ * DIM;
      #pragma unroll
      for (int i = 0; i < 4; ++i) {
        const int r = wave + i * 4;
        GLD16(src + (size_t)r * DIM + lane * 4, &tile[cur ^ 1][r * LROW]);
      }
    }

    // --- dot products: group g handles row g;  s = sum_d ctx[j,d]*qv[d] ---
    {
      const float* trow = &tile[cur][grp * LROW];
      float p = 0.f;
      #pragma unroll
      for (int k = 0; k < TJ; ++k) {
        const int d = gl + 16 * k;
        p += trow[d] * qv[d];            // tile: 2-way banks; qv: broadcast
      }
      p += __shfl_xor(p, 1);
      p += __shfl_xor(p, 2);
      p += __shfl_xor(p, 4);
      p += __shfl_xor(p, 8);
      if (gl == 0) sc_all[t * TJ + grp] = p;
    }

    // lgkm-only barrier: publishes sc_all without draining the vmcnt prefetch
    asm volatile("s_waitcnt lgkmcnt(0)\n\ts_barrier" ::: "memory");

    // --- online softmax update (redundant per thread, consistent) ---
    {
      const float* sct = &sc_all[t * TJ];
      float tm = m;
      #pragma unroll
      for (int j = 0; j < TJ; ++j) tm = fmaxf(tm, sct[j]);
      const float rsc = __expf(m - tm);  // exp(-inf)=0 on first tile
      m = tm;
      l    *= rsc;
      accA *= rsc;
      accB *= rsc;
      const float* tb  = &tile[cur][tid];
      const float  dt0 = (float)(QLEN - 1 - t * TJ);
      #pragma unroll
      for (int j = 0; j < TJ; ++j) {
        const float w   = __expf(sct[j] - m);
        l += w;
        const float cv  = tb[j * LROW];
        const float btj = __expf(-ab_v * (dt0 - (float)j));
        accA += w * cv;
        accB += w * btj * fabsf(cv);
      }
    }
  }

  // epilogue: mix2 = tanh(A/l + (|ae|-|ad|) * B/l)
  const float inv_l = 1.f / l;
  const float cb    = fabsf(ae[b]) - fabsf(ad[b]);
  mix2_ws[b * DIM + tid] = tanhf(accA * inv_l + cb * (accB * inv_l));
  if (tid == 0) { ml_ws[2 * b] = m; ml_ws[2 * b + 1] = l; }

  __syncthreads();   // all sc_all writes visible
  #pragma unroll
  for (int c = 0; c < 4; ++c)
    scores_out[(size_t)b * QLEN + c * 256 + tid] = sc_all[c * 256 + tid];
}

// ---------------------------------------------------------------------------
// K2: out[b,d] = tanh( [mix2 ; q] . W_out[d,:] )      (W_out [D,2D], L2-resident)
// ---------------------------------------------------------------------------
__global__ __launch_bounds__(256) void out_gemm_kernel(
    const float* __restrict__ W_out,
    const float* __restrict__ q_ws,
    const float* __restrict__ mix2_ws,
    float* __restrict__ out)
{
  __shared__ float comb[2 * DIM];
  const int b = blockIdx.x, tid = threadIdx.x;
  comb[tid]       = mix2_ws[b * DIM + tid];
  comb[DIM + tid] = q_ws[b * DIM + tid];
  __syncthreads();

  const float4* w4 = (const float4*)(W_out + (size_t)tid * 2 * DIM);
  float acc = 0.f;
  #pragma unroll 8
  for (int k = 0; k < (2 * DIM) / 4; ++k) {
    const float4 wv = w4[k];
    acc += wv.x * comb[4 * k] + wv.y * comb[4 * k + 1] +
           wv.z * comb[4 * k + 2] + wv.w * comb[4 * k + 3];
  }
  out[(size_t)b * DIM + tid] = tanhf(acc);
}

// ---------------------------------------------------------------------------
// K3: normalize raw scores in place: attn = exp(s - m)/l
// ---------------------------------------------------------------------------
__global__ __launch_bounds__(256) void attn_norm_kernel(
    float* __restrict__ scores, const float* __restrict__ ml)
{
  const int i = blockIdx.x * blockDim.x + threadIdx.x;   // exact N*Q grid
  const int b = i >> 10;                                  // /QLEN
  const float m = ml[2 * b], l = ml[2 * b + 1];
  scores[i] = __expf(scores[i] - m) / l;
}

// ---------------------------------------------------------------------------
extern "C" void kernel_launch(void* const* d_in, const int* in_sizes, int n_in,
                              void* d_out, int out_size, void* d_ws, size_t ws_size,
                              hipStream_t stream) {
  const float* query   = (const float*)d_in[0];
  const float* context = (const float*)d_in[1];
  const float* W_in    = (const float*)d_in[2];
  const float* W_out   = (const float*)d_in[3];
  const float* ae      = (const float*)d_in[4];
  const float* ad      = (const float*)d_in[5];
  const float* ab      = (const float*)d_in[6];
  // d_in[7] = index (unused)

  float* out        = (float*)d_out;                       // [N,1,D]
  float* scores_out = (float*)d_out + N_NODES * DIM;       // [N,1,Q]

  float* q_ws    = (float*)d_ws;                           // [N,D]
  float* mix2_ws = q_ws + N_NODES * DIM;                   // [N,D]
  float* ml_ws   = mix2_ws + N_NODES * DIM;                // [N,2]

  hipLaunchKernelGGL(attn_main_kernel, dim3(N_NODES), dim3(256), 0, stream,
                     query, context, W_in, ae, ad, ab,
                     scores_out, q_ws, mix2_ws, ml_ws);
  hipLaunchKernelGGL(out_gemm_kernel, dim3(N_NODES), dim3(256), 0, stream,
                     W_out, q_ws, mix2_ws, out);
  hipLaunchKernelGGL(attn_norm_kernel, dim3((N_NODES * QLEN) / 256), dim3(256), 0, stream,
                     scores_out, ml_ws);
}

// Round 4
// 724.766 us; speedup vs baseline: 1.0291x; 1.0291x over previous
//
#include <hip/hip_runtime.h>
#include <math.h>

#define N_NODES 512
#define QLEN    1024
#define DIM     256
#define TJ      16             // context rows per tile
#define LROW    264            // padded LDS row stride; 264%32==8 -> 2-way aliasing (free)
#define NT      (QLEN / TJ)    // 64 tiles
#define NBUF    3              // triple buffer, prefetch depth 2

#define AS1 __attribute__((address_space(1)))
#define AS3 __attribute__((address_space(3)))
#define GLD16(gsrc, ldst) \
  __builtin_amdgcn_global_load_lds((AS1 const void*)(gsrc), (AS3 void*)(ldst), 16, 0, 0)

// One block per node, 256 threads (4 waves). Fully fused:
//   q = query@W_in^T ; scores = q.ctx ; softmax ; A=sum w*c, B=sum w*bt*|c| ;
//   mix2 = tanh((A + (|ae|-|ad|)*B)/L) ; out = tanh([mix2;q]@W_out^T) ; attn weights.
// Wave-private tile stripes: wave w stages AND reads rows 4w..4w+3 only ->
// no in-loop barriers. Per-wave online softmax, flash-style merge at the end.
__global__ __launch_bounds__(256, 2) void rpps_fused_kernel(
    const float* __restrict__ query,    // [N,1,D]
    const float* __restrict__ context,  // [N,Q,D]
    const float* __restrict__ W_in,     // [D,D]
    const float* __restrict__ W_out,    // [D,2D]
    const float* __restrict__ ae,
    const float* __restrict__ ad,
    const float* __restrict__ ab,
    float* __restrict__ out,            // [N,D]
    float* __restrict__ scores_out)     // [N,Q]
{
  __shared__ float qs[DIM];
  __shared__ float qv[DIM];
  __shared__ float sc[QLEN];                // raw scores for this node
  __shared__ float comb[2 * DIM];           // [mix2 ; q]
  __shared__ float redM[4], redL[4];        // per-wave merge state
  __shared__ float redA[4][DIM], redB[4][DIM];
  __shared__ float tile[NBUF][TJ * LROW];   // triple-buffered context tile

  const int b    = blockIdx.x;
  const int tid  = threadIdx.x;
  const int wave = tid >> 6;
  const int lane = tid & 63;
  const int wg   = (tid >> 4) & 3;   // group within wave
  const int gl   = tid & 15;         // lane within 16-lane dot group
  const int row  = 4 * wave + wg;    // tile row this group owns

  const float* ctx = context + (size_t)b * QLEN * DIM;

  qs[tid] = query[b * DIM + tid];

  // depth-2 prefetch: tiles 0 and 1 (each wave stages exactly its own rows)
  #pragma unroll
  for (int i = 0; i < 4; ++i)
    GLD16(ctx + (size_t)(4 * wave + i) * DIM + lane * 4,
          &tile[0][(4 * wave + i) * LROW]);
  #pragma unroll
  for (int i = 0; i < 4; ++i)
    GLD16(ctx + (size_t)(TJ + 4 * wave + i) * DIM + lane * 4,
          &tile[1][(4 * wave + i) * LROW]);

  // lgkm-only barrier: qs visible, prefetch stays in flight
  asm volatile("s_waitcnt lgkmcnt(0)\n\ts_barrier" ::: "memory");

  // q projection: qp = W_in[tid,:] . qs
  float qp = 0.f;
  {
    const float4* w4 = (const float4*)(W_in + (size_t)tid * DIM);
    #pragma unroll 8
    for (int k = 0; k < DIM / 4; ++k) {
      const float4 wv = w4[k];
      qp += wv.x * qs[4 * k] + wv.y * qs[4 * k + 1] +
            wv.z * qs[4 * k + 2] + wv.w * qs[4 * k + 3];
    }
  }
  qv[tid] = qp;
  asm volatile("s_waitcnt lgkmcnt(0)\n\ts_barrier" ::: "memory");

  float qreg[16];
  #pragma unroll
  for (int k = 0; k < 16; ++k) qreg[k] = qv[gl + 16 * k];   // my dims, in regs

  const float ab_v = ab[b];
  float m_w = -INFINITY, l_w = 0.f;
  float accA[16], accB[16];
  #pragma unroll
  for (int k = 0; k < 16; ++k) { accA[k] = 0.f; accB[k] = 0.f; }

  int slot_c = 0, slot_p = 2;
  for (int t = 0; t < NT; ++t) {
    // my 4 rows of tile t are the 4 oldest of my <=8 outstanding loads
    if (t < NT - 1) asm volatile("s_waitcnt vmcnt(4)" ::: "memory");
    else            asm volatile("s_waitcnt vmcnt(0)" ::: "memory");

    // issue prefetch of tile t+2 (wave-private rows -> no barrier needed:
    // my last read of this slot was 2 iterations ago, in my program order)
    if (t + 2 < NT) {
      const float* src = ctx + (size_t)(t + 2) * TJ * DIM;
      float* dst = &tile[slot_p][0];
      #pragma unroll
      for (int i = 0; i < 4; ++i)
        GLD16(src + (size_t)(4 * wave + i) * DIM + lane * 4,
              dst + (4 * wave + i) * LROW);
    }

    // read my 16 elems of row `row` (dims gl+16k) into registers
    const float* trow = &tile[slot_c][row * LROW + gl];
    float c[16];
    #pragma unroll
    for (int k = 0; k < 16; ++k) c[k] = trow[16 * k];

    // score: 16-lane group dot
    float s = 0.f;
    #pragma unroll
    for (int k = 0; k < 16; ++k) s += c[k] * qreg[k];
    s += __shfl_xor(s, 1);
    s += __shfl_xor(s, 2);
    s += __shfl_xor(s, 4);
    s += __shfl_xor(s, 8);

    if (gl == 0) sc[t * TJ + row] = s;   // raw score, unique addr per (t,row)

    // wave-local tile max over the 4 groups
    float tm = fmaxf(s, __shfl_xor(s, 16));
    tm = fmaxf(tm, __shfl_xor(tm, 32));

    if (tm > m_w) {                       // exact skip: rsc==1 otherwise
      const float rsc = __expf(m_w - tm); // exp(-inf)=0 on first tile
      m_w = tm;
      l_w *= rsc;
      #pragma unroll
      for (int k = 0; k < 16; ++k) { accA[k] *= rsc; accB[k] *= rsc; }
    }

    const float w  = __expf(s - m_w);
    const float bt = __expf(-ab_v * (float)(QLEN - 1 - (t * TJ + row)));
    const float wb = w * bt;
    l_w += w;
    #pragma unroll
    for (int k = 0; k < 16; ++k) {
      accA[k] += w * c[k];
      accB[k] += wb * fabsf(c[k]);
    }

    if (++slot_c == NBUF) slot_c = 0;
    if (++slot_p == NBUF) slot_p = 0;
  }

  // ---- intra-wave reduce over the 4 groups (same wave-local m) ----
  #pragma unroll
  for (int k = 0; k < 16; ++k) {
    accA[k] += __shfl_xor(accA[k], 16);
    accA[k] += __shfl_xor(accA[k], 32);
    accB[k] += __shfl_xor(accB[k], 16);
    accB[k] += __shfl_xor(accB[k], 32);
  }
  l_w += __shfl_xor(l_w, 16);
  l_w += __shfl_xor(l_w, 32);

  if (lane == 0) { redM[wave] = m_w; redL[wave] = l_w; }
  if (wg == 0) {
    #pragma unroll
    for (int k = 0; k < 16; ++k) {
      redA[wave][gl + 16 * k] = accA[k];
      redB[wave][gl + 16 * k] = accB[k];
    }
  }
  __syncthreads();   // red* and all sc writes visible

  // ---- cross-wave flash merge ----
  const float M  = fmaxf(fmaxf(redM[0], redM[1]), fmaxf(redM[2], redM[3]));
  const float e0 = __expf(redM[0] - M), e1 = __expf(redM[1] - M);
  const float e2 = __expf(redM[2] - M), e3 = __expf(redM[3] - M);
  const float L  = e0 * redL[0] + e1 * redL[1] + e2 * redL[2] + e3 * redL[3];
  const float A  = e0 * redA[0][tid] + e1 * redA[1][tid] +
                   e2 * redA[2][tid] + e3 * redA[3][tid];
  const float B  = e0 * redB[0][tid] + e1 * redB[1][tid] +
                   e2 * redB[2][tid] + e3 * redB[3][tid];
  const float invL = 1.f / L;
  const float cb   = fabsf(ae[b]) - fabsf(ad[b]);

  comb[tid]       = tanhf((A + cb * B) * invL);   // mix2
  comb[DIM + tid] = qp;                           // projected q (register)

  // normalized attention weights (coalesced, 4 per thread)
  #pragma unroll
  for (int c2 = 0; c2 < 4; ++c2) {
    const int j = c2 * 256 + tid;
    scores_out[(size_t)b * QLEN + j] = __expf(sc[j] - M) * invL;
  }

  __syncthreads();   // comb visible

  // ---- out = tanh([mix2;q] @ W_out^T), W_out row tid from L2 ----
  float oacc = 0.f;
  {
    const float4* wo4 = (const float4*)(W_out + (size_t)tid * 2 * DIM);
    #pragma unroll 8
    for (int k = 0; k < (2 * DIM) / 4; ++k) {
      const float4 wv = wo4[k];
      oacc += wv.x * comb[4 * k] + wv.y * comb[4 * k + 1] +
              wv.z * comb[4 * k + 2] + wv.w * comb[4 * k + 3];
    }
  }
  out[(size_t)b * DIM + tid] = tanhf(oacc);
}

// ---------------------------------------------------------------------------
extern "C" void kernel_launch(void* const* d_in, const int* in_sizes, int n_in,
                              void* d_out, int out_size, void* d_ws, size_t ws_size,
                              hipStream_t stream) {
  const float* query   = (const float*)d_in[0];
  const float* context = (const float*)d_in[1];
  const float* W_in    = (const float*)d_in[2];
  const float* W_out   = (const float*)d_in[3];
  const float* ae      = (const float*)d_in[4];
  const float* ad      = (const float*)d_in[5];
  const float* ab      = (const float*)d_in[6];
  // d_in[7] = index (unused)

  float* out        = (float*)d_out;                   // [N,1,D]
  float* scores_out = (float*)d_out + N_NODES * DIM;   // [N,1,Q]

  hipLaunchKernelGGL(rpps_fused_kernel, dim3(N_NODES), dim3(256), 0, stream,
                     query, context, W_in, W_out, ae, ad, ab, out, scores_out);
}